// Round 2
// baseline (339.592 us; speedup 1.0000x reference)
//
#include <hip/hip_runtime.h>
#include <hip/hip_cooperative_groups.h>

namespace cg = cooperative_groups;

// Problem constants
#define NT 10          // trees
#define NL 16          // leaves per tree
#define NN 31          // nodes per tree
#define DD 256         // hidden dim
#define G4 1024        // 4*D gates
#define NNODES (NT*NN) // 310
#define NPATH (NT*NL)  // 160
#define NB 4096        // batch
#define NROWS (NB*NT)  // 40960 output rows

// ws layout (floats): xg[310][1024] | hA[160][256] | hB[160][256] | cB[160][256]

__device__ __forceinline__ float sigf(float x)   { return 1.0f / (1.0f + __expf(-x)); }
__device__ __forceinline__ float tanh_f(float x) { return 2.0f / (1.0f + __expf(-2.0f*x)) - 1.0f; }

// One LSTM GEMM step for one (path, d): 4 gate dots of K=256 against h (LDS),
// W_hh rows direct from global (L2-resident, 4-way lane dup = 256B unique/load).
__device__ __forceinline__ void lstm_gemm(
    const float4* __restrict__ Whh4, const float* __restrict__ xg,
    const float4* __restrict__ hrow, int node, int d, float c_in,
    float& c_out, float& h_out)
{
    const float4* wi = Whh4 + (size_t)(d)       * 64;
    const float4* wf = Whh4 + (size_t)(256 + d) * 64;
    const float4* wg = Whh4 + (size_t)(512 + d) * 64;
    const float4* wo = Whh4 + (size_t)(768 + d) * 64;
    float ai = 0.f, af = 0.f, ag = 0.f, ao = 0.f;
    #pragma unroll 8
    for (int kc = 0; kc < 64; ++kc) {
        float4 h = hrow[kc];
        float4 vi = wi[kc], vf = wf[kc], vg = wg[kc], vo = wo[kc];
        ai = fmaf(h.x, vi.x, fmaf(h.y, vi.y, fmaf(h.z, vi.z, fmaf(h.w, vi.w, ai))));
        af = fmaf(h.x, vf.x, fmaf(h.y, vf.y, fmaf(h.z, vf.z, fmaf(h.w, vf.w, af))));
        ag = fmaf(h.x, vg.x, fmaf(h.y, vg.y, fmaf(h.z, vg.z, fmaf(h.w, vg.w, ag))));
        ao = fmaf(h.x, vo.x, fmaf(h.y, vo.y, fmaf(h.z, vo.z, fmaf(h.w, vo.w, ao))));
    }
    const float* xn = xg + (size_t)node * G4;
    float gi = ai + xn[d];
    float gf = af + xn[256 + d];
    float gg = ag + xn[512 + d];
    float go = ao + xn[768 + d];
    c_out = sigf(gf) * c_in + sigf(gi) * tanh_f(gg);
    h_out = sigf(go) * tanh_f(c_out);
}

// Single cooperative kernel: nodeproj -> 5 LSTM steps -> scatter.
// grid = 256 blocks x 256 threads (1 block/CU co-resident), 5 grid syncs.
__global__ __launch_bounds__(256) void k_fused(
    const float* __restrict__ cross, const float* __restrict__ emb,
    const float* __restrict__ Wih,   const float* __restrict__ Whh,
    const float* __restrict__ bih,   const float* __restrict__ bhh,
    float* __restrict__ out, float* __restrict__ ws)
{
    __shared__ float4 smem[20 * 64];   // 20 KB, reused across phases
    float* xg = ws;
    float* hA = xg + NNODES * G4;
    float* hB = hA + NPATH * DD;
    float* cB = hB + NPATH * DD;

    cg::grid_group grid = cg::this_grid();
    const int tid = threadIdx.x;
    const int bid = blockIdx.x;

    // ---------------- Phase 1: xg[n][j] = emb[n].Wih[j] + bih[j] + bhh[j] ----
    // bid = (ng 0..15) * 16 + (jt 0..15); block: 20 nodes x 64 gate dims,
    // thread = (nsub 0..3 -> 5 nodes, j lane 0..63). emb tile staged in LDS.
    {
        const int jt = bid & 15, ng = bid >> 4;
        const float4* emb4 = (const float4*)emb;
        #pragma unroll
        for (int r = 0; r < 5; ++r) {
            int idx = tid + 256 * r;                 // 0..1279
            int n = ng * 20 + (idx >> 6);
            smem[idx] = (n < NNODES) ? emb4[(size_t)n * 64 + (idx & 63)]
                                     : make_float4(0.f, 0.f, 0.f, 0.f);
        }
        __syncthreads();
        const int j    = jt * 64 + (tid & 63);
        const int nsub = tid >> 6;                   // 0..3
        const float4* W4 = (const float4*)Wih + (size_t)j * 64;
        const float4* e0 = smem + (nsub * 5 + 0) * 64;
        const float4* e1 = smem + (nsub * 5 + 1) * 64;
        const float4* e2 = smem + (nsub * 5 + 2) * 64;
        const float4* e3 = smem + (nsub * 5 + 3) * 64;
        const float4* e4 = smem + (nsub * 5 + 4) * 64;
        float a0 = 0.f, a1 = 0.f, a2 = 0.f, a3 = 0.f, a4 = 0.f;
        #pragma unroll 4
        for (int kc = 0; kc < 64; ++kc) {
            float4 w = W4[kc];
            float4 v0 = e0[kc], v1 = e1[kc], v2 = e2[kc], v3 = e3[kc], v4 = e4[kc];
            a0 = fmaf(w.x, v0.x, fmaf(w.y, v0.y, fmaf(w.z, v0.z, fmaf(w.w, v0.w, a0))));
            a1 = fmaf(w.x, v1.x, fmaf(w.y, v1.y, fmaf(w.z, v1.z, fmaf(w.w, v1.w, a1))));
            a2 = fmaf(w.x, v2.x, fmaf(w.y, v2.y, fmaf(w.z, v2.z, fmaf(w.w, v2.w, a2))));
            a3 = fmaf(w.x, v3.x, fmaf(w.y, v3.y, fmaf(w.z, v3.z, fmaf(w.w, v3.w, a3))));
            a4 = fmaf(w.x, v4.x, fmaf(w.y, v4.y, fmaf(w.z, v4.z, fmaf(w.w, v4.w, a4))));
        }
        const float bsum = bih[j] + bhh[j];
        const float acc[5] = {a0, a1, a2, a3, a4};
        #pragma unroll
        for (int r = 0; r < 5; ++r) {
            int n = ng * 20 + nsub * 5 + r;
            if (n < NNODES) xg[(size_t)n * G4 + j] = acc[r] + bsum;
        }
    }
    grid.sync();

    // ---------------- Phase 2: LSTM over 160 paths, 5 positions ----
    // bid = (pg 0..15) * 16 + (dtile 0..15); block: 10 paths x 16 dims.
    // thread = (pl = tid>>4 [active if <10], lane_d = tid&15).
    // h tile in LDS, rows padded to 65 float4 (260 floats) to break bank aliasing.
    {
        const int dtile  = bid & 15;
        const int pg     = bid >> 4;
        const int pl     = tid >> 4;
        const int lane_d = tid & 15;
        const int p      = pg * 10 + pl;          // 0..159 when active
        const bool act   = (pl < 10);
        const int t = p >> 4, l = p & 15;
        const int d = dtile * 16 + lane_d;
        float* hs = (float*)smem;                 // 260-float rows
        const float4* Whh4 = (const float4*)Whh;

        // Position 0 (h0=c0=0, pure elementwise on the shared root row) fused
        // with position-1 GEMM. h1 computed directly into LDS.
        float c_keep = 0.f;
        if (act) {
            const float* xr = xg + (size_t)(t * NN) * G4;   // root node row
            #pragma unroll
            for (int i = 0; i < 16; ++i) {
                int k = lane_d + 16 * i;
                float gi = xr[k], gg = xr[512 + k], go = xr[768 + k];
                float c1 = sigf(gi) * tanh_f(gg);           // c0 = 0
                float h1 = sigf(go) * tanh_f(c1);
                hs[pl * 260 + k] = h1;
                if (i == dtile) c_keep = c1;
            }
        }
        __syncthreads();
        if (act) {
            int off = 1 + (l >> 3);                         // position 1 node
            float cn, hn;
            lstm_gemm(Whh4, xg, smem + pl * 65, t * NN + off, d, c_keep, cn, hn);
            cB[(size_t)p * DD + d] = cn;
            hA[(size_t)p * DD + d] = hn;
        }
        grid.sync();

        // Positions 2..4
        const float* hin_buf[3]  = { hA, hB, hA };
        float*       hout_buf[3] = { hB, hA, hB };
        #pragma unroll
        for (int s = 0; s < 3; ++s) {
            const int si = s + 2;
            const float4* hin4 = (const float4*)hin_buf[s];
            for (int idx = tid; idx < 640; idx += 256)      // 10 paths x 64 f4
                smem[(idx >> 6) * 65 + (idx & 63)] = hin4[(size_t)pg * 640 + idx];
            float c_in = act ? cB[(size_t)p * DD + d] : 0.f;
            __syncthreads();
            if (act) {
                int off = (1 << si) - 1 + (l >> (4 - si));
                float cn, hn;
                lstm_gemm(Whh4, xg, smem + pl * 65, t * NN + off, d, c_in, cn, hn);
                cB[(size_t)p * DD + d] = cn;
                hout_buf[s][(size_t)p * DD + d] = hn;
            }
            grid.sync();
        }
    }

    // ---------------- Phase 3: scatter out[b,t,:] = hB[t*16 + leaf(b,t), :] ----
    // One wave per (b,t) row, grid-stride (1024 waves x 40 rows).
    {
        const int gw   = bid * 4 + (tid >> 6);
        const int lane = tid & 63;
        const float4* h4 = (const float4*)hB;
        float4* o4 = (float4*)out;
        for (int r = gw; r < NROWS; r += 1024) {
            int b  = r / NT;
            int tt = r - b * NT;
            float v = 0.f;
            if (lane < NL) v = cross[(size_t)b * (NT * NL) + tt * NL + lane];
            unsigned long long m = __ballot(v > 0.5f);
            int leaf = m ? (int)__builtin_ctzll(m) : 0;
            int pp = tt * NL + leaf;
            o4[(size_t)r * 64 + lane] = h4[(size_t)pp * 64 + lane];
        }
    }
}

// ---------------------------------------------------------------------------
extern "C" void kernel_launch(void* const* d_in, const int* in_sizes, int n_in,
                              void* d_out, int out_size, void* d_ws, size_t ws_size,
                              hipStream_t stream)
{
    const float* cross = (const float*)d_in[0];
    const float* emb   = (const float*)d_in[1];
    const float* Wih   = (const float*)d_in[2];
    const float* Whh   = (const float*)d_in[3];
    const float* bih   = (const float*)d_in[4];
    const float* bhh   = (const float*)d_in[5];
    float* out = (float*)d_out;
    float* ws  = (float*)d_ws;

    void* args[] = { (void*)&cross, (void*)&emb, (void*)&Wih, (void*)&Whh,
                     (void*)&bih, (void*)&bhh, (void*)&out, (void*)&ws };
    hipLaunchCooperativeKernel((void*)k_fused, dim3(256), dim3(256),
                               args, 0, stream);
}

// Round 3
// 125.866 us; speedup vs baseline: 2.6980x; 2.6980x over previous
//
#include <hip/hip_runtime.h>

#define NT 10          // trees
#define NL 16          // leaves per tree
#define NN 31          // nodes per tree
#define DD 256         // hidden dim
#define G4 1024        // 4*D gates
#define NNODES (NT*NN) // 310
#define NPATH (NT*NL)  // 160
#define NB 4096
#define NROWS (NB*NT)  // 40960 output rows

// ws layout (floats): xg[310][1024] | hA[160][256] | hB[160][256] | cB[160][256]

__device__ __forceinline__ float sigf(float x)   { return 1.0f / (1.0f + __expf(-x)); }
__device__ __forceinline__ float tanh_f(float x) { return 2.0f / (1.0f + __expf(-2.0f*x)) - 1.0f; }

// ---------------------------------------------------------------------------
// Node projection: xg[n][j] = emb[n].Wih_row[j] + bih[j] + bhh[j]
// grid 256 = (mt 0..15 [20 nodes]) x (nt 0..15 [64 W rows]).
// Thread (kq=tid>>6, w=tid&63) holds Wih[nt*64+w][kq*64..+64] in 16 f4 REGS.
// emb tile in LDS, read as same-address broadcasts. kq-reduction via LDS.
// ---------------------------------------------------------------------------
__global__ __launch_bounds__(256) void k_nodeproj(
    const float* __restrict__ emb, const float* __restrict__ Wih,
    const float* __restrict__ bih, const float* __restrict__ bhh,
    float* __restrict__ xg)
{
    __shared__ float smem[20 * 260 + 20 * 4 * 64];   // emb tile | partials
    float4* es4 = (float4*)smem;                      // rows padded to 65 f4
    float*  ps  = smem + 20 * 260;                    // [(m*4+kq)*64 + w]

    const int tid = threadIdx.x;
    const int nt  = blockIdx.x & 15;
    const int mt  = blockIdx.x >> 4;
    const int kq  = tid >> 6;
    const int w   = tid & 63;

    // W row quarter -> registers (one-time gather)
    const float4* W4 = (const float4*)Wih + (size_t)(nt * 64 + w) * 64 + kq * 16;
    float4 wreg[16];
    #pragma unroll
    for (int j = 0; j < 16; ++j) wreg[j] = W4[j];

    // stage 20 emb rows into LDS (coalesced)
    const float4* emb4 = (const float4*)emb;
    #pragma unroll
    for (int r = 0; r < 5; ++r) {
        int idx = tid + 256 * r;                      // 0..1279
        int m = idx >> 6, q = idx & 63;
        int n = mt * 20 + m;
        es4[m * 65 + q] = (n < NNODES) ? emb4[(size_t)n * 64 + q]
                                       : make_float4(0.f, 0.f, 0.f, 0.f);
    }
    __syncthreads();

    float acc[20];
    #pragma unroll
    for (int m = 0; m < 20; ++m) acc[m] = 0.f;
    #pragma unroll
    for (int j = 0; j < 16; ++j) {
        float4 wv = wreg[j];
        #pragma unroll
        for (int m = 0; m < 20; ++m) {
            float4 h = es4[m * 65 + kq * 16 + j];     // broadcast
            acc[m] = fmaf(wv.x, h.x, fmaf(wv.y, h.y,
                     fmaf(wv.z, h.z, fmaf(wv.w, h.w, acc[m]))));
        }
    }
    #pragma unroll
    for (int m = 0; m < 20; ++m) ps[(m * 4 + kq) * 64 + w] = acc[m];
    __syncthreads();

    // 1280 outputs / 256 threads = 5 each; lanes sweep nl -> coalesced write
    const int nl   = tid & 63;
    const int msub = tid >> 6;
    const int j    = nt * 64 + nl;
    const float bsum = bih[j] + bhh[j];
    #pragma unroll
    for (int r = 0; r < 5; ++r) {
        int m = msub * 5 + r;
        int n = mt * 20 + m;
        float s = ps[(m * 4 + 0) * 64 + nl] + ps[(m * 4 + 1) * 64 + nl]
                + ps[(m * 4 + 2) * 64 + nl] + ps[(m * 4 + 3) * 64 + nl];
        if (n < NNODES) xg[(size_t)n * G4 + j] = s + bsum;
    }
}

// ---------------------------------------------------------------------------
// LSTM step. grid 256 = (pg 0..15 [10 paths]) x (dtile 0..15 [16 dims]).
// Thread (kq=tid>>6, w=tid&63; gate=w>>4, dl=w&15) holds
// Whh[gate*256 + dtile*16 + dl][kq*64..+64] in 16 f4 REGS.
// h[10][256] in LDS (broadcast reads). kq-reduction via LDS; threads<160 do
// the activations; c round-trips through global cB.
// FIRST fuses position 0 (h0=c0=0, elementwise on the tree root row).
// ---------------------------------------------------------------------------
template<int SI, bool FIRST>
__global__ __launch_bounds__(256) void k_step(
    const float* __restrict__ xg, const float* __restrict__ Whh,
    const float* __restrict__ h_in, float* __restrict__ h_out,
    float* __restrict__ cB)
{
    __shared__ float smem[10 * 260 + 10 * 4 * 64];   // h tile | partials
    float4* hs4 = (float4*)smem;                      // rows padded to 65 f4
    float*  hs  = smem;
    float*  ps  = smem + 10 * 260;                    // [(p*4+kq)*64 + w]

    const int tid   = threadIdx.x;
    const int pg    = blockIdx.x >> 4;
    const int dtile = blockIdx.x & 15;
    const int kq    = tid >> 6;
    const int w     = tid & 63;
    const int gate  = w >> 4;
    const int dlw   = w & 15;

    // Whh row quarter -> registers (one-time gather)
    const float4* W4 = (const float4*)Whh
        + (size_t)(gate * 256 + dtile * 16 + dlw) * 64 + kq * 16;
    float4 wreg[16];
    #pragma unroll
    for (int j = 0; j < 16; ++j) wreg[j] = W4[j];

    if (FIRST) {
        // position 0: h1/c1 from the tree-root xg row, written into LDS
        #pragma unroll
        for (int r = 0; r < 10; ++r) {                // p == r, k == tid... no:
            int p = r;                                // i = r*256+tid -> row r
            int k = tid;
            int t = (pg * 10 + p) >> 4;
            const float* xr = xg + (size_t)(t * NN) * G4;
            float c1 = sigf(xr[k]) * tanh_f(xr[512 + k]);
            float h1 = sigf(xr[768 + k]) * tanh_f(c1);
            hs[p * 260 + k] = h1;
        }
    } else {
        const float4* hin4 = (const float4*)h_in;
        #pragma unroll
        for (int r = 0; r < 3; ++r) {
            int idx = tid + 256 * r;                  // 0..639
            if (idx < 640)
                hs4[(idx >> 6) * 65 + (idx & 63)] = hin4[(size_t)pg * 640 + idx];
        }
    }
    __syncthreads();

    float acc[10];
    #pragma unroll
    for (int p = 0; p < 10; ++p) acc[p] = 0.f;
    #pragma unroll
    for (int j = 0; j < 16; ++j) {
        float4 wv = wreg[j];
        #pragma unroll
        for (int p = 0; p < 10; ++p) {
            float4 h = hs4[p * 65 + kq * 16 + j];     // broadcast
            acc[p] = fmaf(wv.x, h.x, fmaf(wv.y, h.y,
                     fmaf(wv.z, h.z, fmaf(wv.w, h.w, acc[p]))));
        }
    }
    #pragma unroll
    for (int p = 0; p < 10; ++p) ps[(p * 4 + kq) * 64 + w] = acc[p];
    __syncthreads();

    if (tid < 160) {
        const int p  = tid >> 4;
        const int dl = tid & 15;
        const int d  = dtile * 16 + dl;
        const int pglob = pg * 10 + p;
        const int t = pglob >> 4, l = pglob & 15;
        int off;
        if      (SI == 1) off = 1  + (l >> 3);
        else if (SI == 2) off = 3  + (l >> 2);
        else if (SI == 3) off = 7  + (l >> 1);
        else              off = 15 + l;
        const float* xn = xg + (size_t)(t * NN + off) * G4;

        float g0 = 0.f, g1 = 0.f, g2 = 0.f, g3 = 0.f;
        #pragma unroll
        for (int q = 0; q < 4; ++q) {
            g0 += ps[(p * 4 + q) * 64 +  0 + dl];
            g1 += ps[(p * 4 + q) * 64 + 16 + dl];
            g2 += ps[(p * 4 + q) * 64 + 32 + dl];
            g3 += ps[(p * 4 + q) * 64 + 48 + dl];
        }
        float c_in;
        if (FIRST) {
            int tt = pglob >> 4;
            const float* xr = xg + (size_t)(tt * NN) * G4;
            c_in = sigf(xr[d]) * tanh_f(xr[512 + d]);
        } else {
            c_in = cB[(size_t)pglob * DD + d];
        }
        float gi = g0 + xn[d];
        float gf = g1 + xn[256 + d];
        float gg = g2 + xn[512 + d];
        float go = g3 + xn[768 + d];
        float cn = sigf(gf) * c_in + sigf(gi) * tanh_f(gg);
        float hn = sigf(go) * tanh_f(cn);
        cB[(size_t)pglob * DD + d]    = cn;
        h_out[(size_t)pglob * DD + d] = hn;
    }
}

// ---------------------------------------------------------------------------
// Scatter: out[b,t,:] = htab[t*16 + argmax(cross[b,t,:]), :]
// One wave per (b,t) row: ballot finds the one-hot leaf, float4 row copy.
// ---------------------------------------------------------------------------
__global__ __launch_bounds__(256) void k_scatter(
    const float* __restrict__ cross, const float* __restrict__ htab,
    float* __restrict__ out)
{
    const int tid  = threadIdx.x;
    const int wave = tid >> 6;
    const int lane = tid & 63;
    const int r = blockIdx.x * 4 + wave;     // 0..40959 = b*10 + t
    const int b = r / NT;
    const int t = r - b * NT;

    float v = 0.f;
    if (lane < NL) v = cross[(size_t)b * (NT * NL) + t * NL + lane];
    unsigned long long m = __ballot(v > 0.5f);
    int leaf = m ? (int)__builtin_ctzll(m) : 0;
    int p = t * NL + leaf;

    const float4* h4 = (const float4*)htab;
    float4* o4 = (float4*)out;
    o4[(size_t)r * 64 + lane] = h4[(size_t)p * 64 + lane];
}

// ---------------------------------------------------------------------------
extern "C" void kernel_launch(void* const* d_in, const int* in_sizes, int n_in,
                              void* d_out, int out_size, void* d_ws, size_t ws_size,
                              hipStream_t stream)
{
    const float* cross = (const float*)d_in[0];
    const float* emb   = (const float*)d_in[1];
    const float* Wih   = (const float*)d_in[2];
    const float* Whh   = (const float*)d_in[3];
    const float* bih   = (const float*)d_in[4];
    const float* bhh   = (const float*)d_in[5];
    float* out = (float*)d_out;

    float* ws = (float*)d_ws;
    float* xg = ws;                          // 310*1024
    float* hA = xg + NNODES * G4;            // 160*256
    float* hB = hA + NPATH * DD;             // 160*256
    float* cB = hB + NPATH * DD;             // 160*256

    hipLaunchKernelGGL(k_nodeproj, dim3(256), dim3(256), 0, stream,
                       emb, Wih, bih, bhh, xg);
    hipLaunchKernelGGL((k_step<1, true>),  dim3(256), dim3(256), 0, stream,
                       xg, Whh, hA, hA, cB);
    hipLaunchKernelGGL((k_step<2, false>), dim3(256), dim3(256), 0, stream,
                       xg, Whh, hA, hB, cB);
    hipLaunchKernelGGL((k_step<3, false>), dim3(256), dim3(256), 0, stream,
                       xg, Whh, hB, hA, cB);
    hipLaunchKernelGGL((k_step<4, false>), dim3(256), dim3(256), 0, stream,
                       xg, Whh, hA, hB, cB);
    hipLaunchKernelGGL(k_scatter, dim3(10240), dim3(256), 0, stream,
                       cross, hB, out);
}